// Round 1
// 396.813 us; speedup vs baseline: 1.1078x; 1.1078x over previous
//
#include <hip/hip_runtime.h>

#define N_NODES 100000
#define N_PAD   100352        // 392*256
#define N_EDGES 3200000
#define IN_DIM  128
#define HID     64
#define N_GRAPHS 256
#define NB      392           // buckets of 256 dest nodes each
#define NBLK    256           // hist/scatter blocks
#define EPB     (N_EDGES / NBLK)   // 12500
#define G1BLK   (N_NODES / 8)      // 12500 gemm1 blocks

typedef unsigned short ushort_t;
typedef unsigned int   uint_t;

// bf16 helpers: storage-only compression of the gathered operand
__device__ __forceinline__ ushort_t f2bf(float v) {          // round-to-nearest-even
    uint_t b = __float_as_uint(v);
    b += 0x7fffu + ((b >> 16) & 1u);
    return (ushort_t)(b >> 16);
}
__device__ __forceinline__ void bf2f2(uint_t u, float& lo, float& hi) {
    lo = __uint_as_float(u << 16);
    hi = __uint_as_float(u & 0xffff0000u);
}
// 16B load -> 8 floats
__device__ __forceinline__ void ld_bf16x8(const ushort_t* p, float4& a, float4& b) {
    uint4 u = *(const uint4*)p;
    bf2f2(u.x, a.x, a.y); bf2f2(u.y, a.z, a.w);
    bf2f2(u.z, b.x, b.y); bf2f2(u.w, b.z, b.w);
}
// unpack a loaded uint4 (8 bf16) and FMA into the accumulators with weight w
__device__ __forceinline__ void fma8(float4& a0, float4& a1, const uint4& u, float w) {
    float lo, hi;
    bf2f2(u.x, lo, hi); a0.x += lo * w; a0.y += hi * w;
    bf2f2(u.y, lo, hi); a0.z += lo * w; a0.w += hi * w;
    bf2f2(u.z, lo, hi); a1.x += lo * w; a1.y += hi * w;
    bf2f2(u.w, lo, hi); a1.z += lo * w; a1.w += hi * w;
}

// ---------- phase 1 (fused): bucket histogram (blocks 0..NBLK-1) + gemm1 (rest) ----------
__global__ __launch_bounds__(256) void bhist_gemm1_kernel(
        const int* __restrict__ col, int* __restrict__ H,
        const float* __restrict__ x, const float* __restrict__ W1,
        ushort_t* __restrict__ xl) {
    __shared__ int   h[2][NB];           // 3.1 KB
    __shared__ float sW[IN_DIM * HID];   // 32 KB
    __shared__ float sx[8][IN_DIM];      // 4 KB  (union 39 KB -> 4 blocks/CU)
    int tid = threadIdx.x;
    if (blockIdx.x < NBLK) {
        for (int i = tid; i < NB; i += 256) { h[0][i] = 0; h[1][i] = 0; }
        __syncthreads();
        const int4* col4 = (const int4*)col;
        int base4 = blockIdx.x * (EPB / 4);
        int sel = tid & 1;
        for (int j = tid; j < EPB / 4; j += 256) {
            int4 c = col4[base4 + j];
            atomicAdd(&h[sel][c.x >> 8], 1);
            atomicAdd(&h[sel][c.y >> 8], 1);
            atomicAdd(&h[sel][c.z >> 8], 1);
            atomicAdd(&h[sel][c.w >> 8], 1);
        }
        __syncthreads();
        for (int i = tid; i < NB; i += 256) H[i * NBLK + blockIdx.x] = h[0][i] + h[1][i];
    } else {
        int bid = blockIdx.x - NBLK;
        const float4* W4  = (const float4*)W1;
        float4*       sW4 = (float4*)sW;
        #pragma unroll
        for (int i = 0; i < 8; ++i) sW4[tid + 256 * i] = W4[tid + 256 * i];
        int r0 = bid * 8;
        const float4* x4  = (const float4*)(x + (size_t)r0 * IN_DIM);
        float4*       sx4 = (float4*)&sx[0][0];
        sx4[tid] = x4[tid];              // 256 float4 = 8 rows x 128
        __syncthreads();
        int c = tid & 63;
        #pragma unroll
        for (int rep = 0; rep < 2; ++rep) {
            int lr = (tid >> 6) * 2 + rep;   // 0..7
            float acc = 0.f;
            #pragma unroll 8
            for (int k = 0; k < IN_DIM; ++k) acc += sx[lr][k] * sW[k * HID + c];
            xl[(size_t)(r0 + lr) * HID + c] = f2bf(acc);
        }
    }
}

// ---------- phase 2: exclusive scan of H (NB*NBLK, bucket-major) ----------
__global__ __launch_bounds__(256) void scan1_kernel(int* H, int* __restrict__ bsum) {
    __shared__ int s[256];
    int i = blockIdx.x * 256 + threadIdx.x;   // blockIdx.x == bucket (NBLK==256)
    int v = H[i];
    s[threadIdx.x] = v;
    __syncthreads();
    #pragma unroll
    for (int off = 1; off < 256; off <<= 1) {
        int t = (threadIdx.x >= off) ? s[threadIdx.x - off] : 0;
        __syncthreads();
        s[threadIdx.x] += t;
        __syncthreads();
    }
    H[i] = s[threadIdx.x] - v;                           // exclusive within bucket
    if (threadIdx.x == 255) bsum[blockIdx.x] = s[255];   // bucket total
}

// ---------- phase 3: LDS-staged scatter — bucket-sort in LDS, coalesced burst out ----------
// rec = (row | local<<17, ew); local = col & 255 (8 bits), row < 2^17
__global__ __launch_bounds__(256) void bscatter_kernel(const int* __restrict__ row,
                                                       const int* __restrict__ col,
                                                       const float* __restrict__ ew,
                                                       const int* __restrict__ H,
                                                       const int* __restrict__ bsum,
                                                       int* __restrict__ boff,
                                                       int2* __restrict__ recs) {
    __shared__ int2 lrec[EPB];        // 100 KB: the block's records, bucket-sorted
    __shared__ int  lofs[NB];
    __shared__ int  hcnt[NB];
    __shared__ int  gofs[NB];
    __shared__ int  cur[NB];
    __shared__ int  s[256];
    __shared__ int  carry;
    int tid = threadIdx.x, blk = blockIdx.x;
    if (tid == 0) carry = 0;
    __syncthreads();
    for (int c = 0; c < 2; ++c) {                 // 2*256 >= NB
        int i = c * 256 + tid;
        int v = (i < NB) ? bsum[i] : 0;
        s[tid] = v;
        __syncthreads();
        #pragma unroll
        for (int off = 1; off < 256; off <<= 1) {
            int t = (tid >= off) ? s[tid - off] : 0;
            __syncthreads();
            s[tid] += t;
            __syncthreads();
        }
        if (i < NB) {
            int tb = s[tid] - v + carry;          // bucket start in recs
            int ex = H[i * NBLK + blk];
            gofs[i] = tb + ex;
            hcnt[i] = ((blk < NBLK - 1) ? H[i * NBLK + blk + 1] : v) - ex;
            if (blk == 0) boff[i] = tb;
        }
        __syncthreads();
        if (tid == 0) carry += s[255];
        __syncthreads();
    }
    if (tid == 0) carry = 0;
    __syncthreads();
    for (int c = 0; c < 2; ++c) {
        int i = c * 256 + tid;
        int v = (i < NB) ? hcnt[i] : 0;
        s[tid] = v;
        __syncthreads();
        #pragma unroll
        for (int off = 1; off < 256; off <<= 1) {
            int t = (tid >= off) ? s[tid - off] : 0;
            __syncthreads();
            s[tid] += t;
            __syncthreads();
        }
        if (i < NB) { int l = s[tid] - v + carry; lofs[i] = l; cur[i] = l; }
        __syncthreads();
        if (tid == 0) carry += s[255];
        __syncthreads();
    }
    const int4*   row4 = (const int4*)row;
    const int4*   col4 = (const int4*)col;
    const float4* ew4  = (const float4*)ew;
    int base4 = blk * (EPB / 4);
    for (int j = tid; j < EPB / 4; j += 256) {
        int4   r4 = row4[base4 + j];
        int4   c4 = col4[base4 + j];
        float4 w4 = ew4[base4 + j];
        int p0 = atomicAdd(&cur[c4.x >> 8], 1);
        lrec[p0] = make_int2(r4.x | ((c4.x & 255) << 17), __float_as_int(w4.x));
        int p1 = atomicAdd(&cur[c4.y >> 8], 1);
        lrec[p1] = make_int2(r4.y | ((c4.y & 255) << 17), __float_as_int(w4.y));
        int p2 = atomicAdd(&cur[c4.z >> 8], 1);
        lrec[p2] = make_int2(r4.z | ((c4.z & 255) << 17), __float_as_int(w4.z));
        int p3 = atomicAdd(&cur[c4.w >> 8], 1);
        lrec[p3] = make_int2(r4.w | ((c4.w & 255) << 17), __float_as_int(w4.w));
    }
    __syncthreads();
    int wv = tid >> 6, lane = tid & 63;
    for (int i = wv; i < NB; i += 4) {
        int cnt = hcnt[i], lo = lofs[i], go = gofs[i];
        for (int k = lane; k < cnt; k += 64)
            recs[go + k] = lrec[lo + k];
    }
}

// ---------- phase 3.5 (fused): recs pass -> deg+cnt -> dis/rowptr -> csr permutation
// scatter (L2-warm) -> yl scale tail. All block-local after R15's factorization.
__global__ __launch_bounds__(256) void degcsr_kernel(const int2* __restrict__ recs,
                                                     const int* __restrict__ boff,
                                                     float* __restrict__ dis,
                                                     int* __restrict__ rowptr,
                                                     int2* __restrict__ csr,
                                                     ushort_t* xl) {
    __shared__ int   cnt[256];
    __shared__ float degf[256];
    __shared__ int   sscan[256];
    __shared__ int   cur[256];
    int b = blockIdx.x, tid = threadIdx.x;
    cnt[tid] = 0; degf[tid] = 0.f;
    __syncthreads();
    int s = boff[b], e = (b + 1 < NB) ? boff[b + 1] : N_EDGES;
    for (int j = s + tid; j < e; j += 256) {
        int2 r = recs[j];
        int cl = (r.x >> 17) & 255;
        atomicAdd(&cnt[cl], 1);
        atomicAdd(&degf[cl], __int_as_float(r.y));
    }
    __syncthreads();
    int c = cnt[tid];
    sscan[tid] = c;
    __syncthreads();
    #pragma unroll
    for (int off = 1; off < 256; off <<= 1) {
        int t = (tid >= off) ? sscan[tid - off] : 0;
        __syncthreads();
        sscan[tid] += t;
        __syncthreads();
    }
    int rp = s + sscan[tid] - c;                  // exclusive; pad nodes get == e
    rowptr[b * 256 + tid] = rp;
    cur[tid] = rp;
    float d = 1.0f / sqrtf(fmaxf(1.0f + degf[tid], 1e-30f));
    dis[b * 256 + tid] = d;
    __syncthreads();
    degf[tid] = d;                                // reuse as dis cache for the tail
    __syncthreads();
    // csr permutation scatter (bucket's recs are L2-warm from pass 1)
    for (int j = s + tid; j < e; j += 256) {
        int2 r = recs[j];
        int cl = (r.x >> 17) & 255;
        int pos = atomicAdd(&cur[cl], 1);
        csr[pos] = r;                             // gather masks the local bits
    }
    // scale tail: yl = dis * xl for this bucket's 256 rows (coalesced uint4)
    int n0 = b * 256;
    for (int i = tid; i < 256 * 8; i += 256) {    // 8 uint4 chunks per 64-ch row
        int r = i >> 3;
        int n = n0 + r;
        if (n >= N_NODES) break;                  // trailing pad rows
        uint4* p = (uint4*)(xl + (size_t)n * HID) + (i & 7);
        float d2 = degf[r];
        uint4 u = *p;
        float lo, hi;
        uint_t w0, w1, w2, w3;
        bf2f2(u.x, lo, hi); w0 = f2bf(lo * d2) | ((uint_t)f2bf(hi * d2) << 16);
        bf2f2(u.y, lo, hi); w1 = f2bf(lo * d2) | ((uint_t)f2bf(hi * d2) << 16);
        bf2f2(u.z, lo, hi); w2 = f2bf(lo * d2) | ((uint_t)f2bf(hi * d2) << 16);
        bf2f2(u.w, lo, hi); w3 = f2bf(lo * d2) | ((uint_t)f2bf(hi * d2) << 16);
        *p = make_uint4(w0, w1, w2, w3);
    }
}

// ---------- gather core: 16 lanes/node (2 groups of 8), 8 edges in flight/group ----------
// computes yl[n] + sum ew*yl[r] for the lane's 8 channels; includes the single-level
// cross-group reduce (valid in lanes with (lane&15)<8). Caller multiplies by dis[n].
__device__ __forceinline__ void gather_row16(const int2* __restrict__ csr,
                                             const ushort_t* __restrict__ xl,
                                             int base, int end, int n,
                                             int g, int c0,
                                             float4& a0, float4& a1) {
    a0 = make_float4(0.f, 0.f, 0.f, 0.f);
    a1 = make_float4(0.f, 0.f, 0.f, 0.f);
    if (g == 0) {
        ld_bf16x8(xl + (size_t)n * HID + c0, a0, a1);   // self-loop, weight 1
    }
    int j = base + g;
    for (; j + 14 < end; j += 16) {                      // 8 edges in flight
        int2 e0 = csr[j];
        int2 e1 = csr[j + 2];
        int2 e2 = csr[j + 4];
        int2 e3 = csr[j + 6];
        int2 e4 = csr[j + 8];
        int2 e5 = csr[j + 10];
        int2 e6 = csr[j + 12];
        int2 e7 = csr[j + 14];
        uint4 u0 = *(const uint4*)(xl + (size_t)(e0.x & 0x1FFFF) * HID + c0);
        uint4 u1 = *(const uint4*)(xl + (size_t)(e1.x & 0x1FFFF) * HID + c0);
        uint4 u2 = *(const uint4*)(xl + (size_t)(e2.x & 0x1FFFF) * HID + c0);
        uint4 u3 = *(const uint4*)(xl + (size_t)(e3.x & 0x1FFFF) * HID + c0);
        uint4 u4 = *(const uint4*)(xl + (size_t)(e4.x & 0x1FFFF) * HID + c0);
        uint4 u5 = *(const uint4*)(xl + (size_t)(e5.x & 0x1FFFF) * HID + c0);
        uint4 u6 = *(const uint4*)(xl + (size_t)(e6.x & 0x1FFFF) * HID + c0);
        uint4 u7 = *(const uint4*)(xl + (size_t)(e7.x & 0x1FFFF) * HID + c0);
        fma8(a0, a1, u0, __int_as_float(e0.y));
        fma8(a0, a1, u1, __int_as_float(e1.y));
        fma8(a0, a1, u2, __int_as_float(e2.y));
        fma8(a0, a1, u3, __int_as_float(e3.y));
        fma8(a0, a1, u4, __int_as_float(e4.y));
        fma8(a0, a1, u5, __int_as_float(e5.y));
        fma8(a0, a1, u6, __int_as_float(e6.y));
        fma8(a0, a1, u7, __int_as_float(e7.y));
    }
    for (; j + 6 < end; j += 8) {                        // 4 edges in flight
        int2 e0 = csr[j];
        int2 e1 = csr[j + 2];
        int2 e2 = csr[j + 4];
        int2 e3 = csr[j + 6];
        uint4 u0 = *(const uint4*)(xl + (size_t)(e0.x & 0x1FFFF) * HID + c0);
        uint4 u1 = *(const uint4*)(xl + (size_t)(e1.x & 0x1FFFF) * HID + c0);
        uint4 u2 = *(const uint4*)(xl + (size_t)(e2.x & 0x1FFFF) * HID + c0);
        uint4 u3 = *(const uint4*)(xl + (size_t)(e3.x & 0x1FFFF) * HID + c0);
        fma8(a0, a1, u0, __int_as_float(e0.y));
        fma8(a0, a1, u1, __int_as_float(e1.y));
        fma8(a0, a1, u2, __int_as_float(e2.y));
        fma8(a0, a1, u3, __int_as_float(e3.y));
    }
    for (; j < end; j += 2) {                            // singles
        int2 e0 = csr[j];
        uint4 u0 = *(const uint4*)(xl + (size_t)(e0.x & 0x1FFFF) * HID + c0);
        fma8(a0, a1, u0, __int_as_float(e0.y));
    }
    // single-level reduce: combine the two 8-lane groups of this node
    a0.x += __shfl_down(a0.x, 8, 64); a0.y += __shfl_down(a0.y, 8, 64);
    a0.z += __shfl_down(a0.z, 8, 64); a0.w += __shfl_down(a0.w, 8, 64);
    a1.x += __shfl_down(a1.x, 8, 64); a1.y += __shfl_down(a1.y, 8, 64);
    a1.z += __shfl_down(a1.z, 8, 64); a1.w += __shfl_down(a1.w, 8, 64);
}

// ---------- fused gather1 + gemm2: yl2 = dis * (relu(dis*(...) + b1) @ W2) ----------
// 16 nodes per block (4 per wave, 16 lanes each).
__global__ __launch_bounds__(256) void gather_gemm2_kernel(
        const int2* __restrict__ csr, const int* __restrict__ rowptr,
        const float* __restrict__ dis, const ushort_t* __restrict__ xl,
        const float* __restrict__ W2, const float* __restrict__ b1,
        ushort_t* __restrict__ xl2) {
    __shared__ float sW[HID * HID];     // 16 KB
    __shared__ float sh[16][HID + 4];   // pad 68: breaks row-alias on ds_write_b128
    int tid = threadIdx.x;
    const float4* W4  = (const float4*)W2;
    float4*       sW4 = (float4*)sW;
    #pragma unroll
    for (int i = 0; i < 4; ++i) sW4[tid + 256 * i] = W4[tid + 256 * i];

    int n0   = blockIdx.x * 16;
    int wv   = tid >> 6;
    int lane = tid & 63;
    int lr   = wv * 4 + (lane >> 4);     // local row 0..15
    int n    = n0 + lr;
    int g    = (lane >> 3) & 1;
    int c0   = (lane & 7) << 3;
    int base = rowptr[n], end = rowptr[n + 1];
    float d  = dis[n];
    float4 a0, a1;
    gather_row16(csr, xl, base, end, n, g, c0, a0, a1);
    if (g == 0) {
        // h = relu(dis[col]*agg + b1), stored directly (no second pass)
        float4 bb0 = *(const float4*)(b1 + c0);
        float4 bb1 = *(const float4*)(b1 + c0 + 4);
        float4 h0 = make_float4(fmaxf(a0.x * d + bb0.x, 0.f), fmaxf(a0.y * d + bb0.y, 0.f),
                                fmaxf(a0.z * d + bb0.z, 0.f), fmaxf(a0.w * d + bb0.w, 0.f));
        float4 h1 = make_float4(fmaxf(a1.x * d + bb1.x, 0.f), fmaxf(a1.y * d + bb1.y, 0.f),
                                fmaxf(a1.z * d + bb1.z, 0.f), fmaxf(a1.w * d + bb1.w, 0.f));
        *(float4*)(&sh[lr][c0])     = h0;
        *(float4*)(&sh[lr][c0 + 4]) = h1;
    }
    __syncthreads();
    // gemm2: each thread computes 4 rows x 1 col; sW value reused 4x per read
    int cc = tid & 63, rq = tid >> 6;
    float acc0 = 0.f, acc1 = 0.f, acc2 = 0.f, acc3 = 0.f;
    #pragma unroll 8
    for (int k = 0; k < HID; ++k) {
        float wk = sW[k * HID + cc];
        acc0 += sh[rq * 4 + 0][k] * wk;
        acc1 += sh[rq * 4 + 1][k] * wk;
        acc2 += sh[rq * 4 + 2][k] * wk;
        acc3 += sh[rq * 4 + 3][k] * wk;
    }
    xl2[(size_t)(n0 + rq * 4 + 0) * HID + cc] = f2bf(acc0 * dis[n0 + rq * 4 + 0]);
    xl2[(size_t)(n0 + rq * 4 + 1) * HID + cc] = f2bf(acc1 * dis[n0 + rq * 4 + 1]);
    xl2[(size_t)(n0 + rq * 4 + 2) * HID + cc] = f2bf(acc2 * dis[n0 + rq * 4 + 2]);
    xl2[(size_t)(n0 + rq * 4 + 3) * HID + cc] = f2bf(acc3 * dis[n0 + rq * 4 + 3]);
}

// ---------- fused gather2 + pool partial: sval[n] = relu(dis*(...)+b2) . Wc ----------
__global__ __launch_bounds__(256) void gather_pool_kernel(
        const int2* __restrict__ csr, const int* __restrict__ rowptr,
        const float* __restrict__ dis, const ushort_t* __restrict__ xl,
        const float* __restrict__ b2, const float* __restrict__ Wc,
        float* __restrict__ sval) {
    int tid  = threadIdx.x;
    int n    = (blockIdx.x * 256 + tid) >> 4;           // grid 6250 exact
    int lane = tid & 63;
    int g    = (lane >> 3) & 1;
    int c0   = (lane & 7) << 3;
    int base = rowptr[n], end = rowptr[n + 1];
    float d  = dis[n];
    float4 a0, a1;
    gather_row16(csr, xl, base, end, n, g, c0, a0, a1);
    // all lanes compute (g==1 lanes produce garbage that is never read)
    float4 bb0 = *(const float4*)(b2 + c0);
    float4 bb1 = *(const float4*)(b2 + c0 + 4);
    float4 wc0 = *(const float4*)(Wc + c0);
    float4 wc1 = *(const float4*)(Wc + c0 + 4);
    float s = fmaxf(a0.x * d + bb0.x, 0.f) * wc0.x + fmaxf(a0.y * d + bb0.y, 0.f) * wc0.y
            + fmaxf(a0.z * d + bb0.z, 0.f) * wc0.z + fmaxf(a0.w * d + bb0.w, 0.f) * wc0.w
            + fmaxf(a1.x * d + bb1.x, 0.f) * wc1.x + fmaxf(a1.y * d + bb1.y, 0.f) * wc1.y
            + fmaxf(a1.z * d + bb1.z, 0.f) * wc1.z + fmaxf(a1.w * d + bb1.w, 0.f) * wc1.w;
    s += __shfl_down(s, 4, 64);
    s += __shfl_down(s, 2, 64);
    s += __shfl_down(s, 1, 64);
    if ((lane & 15) == 0) sval[n] = s;
}

// ---------- final: out[g] = mean(sval over graph range) + bc ----------
__global__ __launch_bounds__(256) void final_out_kernel(const float* __restrict__ sval,
                                                        const int* __restrict__ batch,
                                                        const float* __restrict__ bc,
                                                        float* __restrict__ out) {
    __shared__ float s[256];
    int g = blockIdx.x;   // grid N_GRAPHS
    int lo = 0, hi = N_NODES;
    while (lo < hi) { int m = (lo + hi) >> 1; if (batch[m] < g) lo = m + 1; else hi = m; }
    int start = lo;
    hi = N_NODES;
    while (lo < hi) { int m = (lo + hi) >> 1; if (batch[m] < g + 1) lo = m + 1; else hi = m; }
    int end = lo;
    float acc = 0.f;
    for (int i = start + threadIdx.x; i < end; i += 256) acc += sval[i];
    s[threadIdx.x] = acc;
    __syncthreads();
    #pragma unroll
    for (int off = 128; off > 0; off >>= 1) {
        if (threadIdx.x < off) s[threadIdx.x] += s[threadIdx.x + off];
        __syncthreads();
    }
    if (threadIdx.x == 0)
        out[g] = s[0] / fmaxf((float)(end - start), 1.0f) + bc[0];
}

extern "C" void kernel_launch(void* const* d_in, const int* in_sizes, int n_in,
                              void* d_out, int out_size, void* d_ws, size_t ws_size,
                              hipStream_t stream) {
    const float* x     = (const float*)d_in[0];
    const int*   ei    = (const int*)  d_in[1];
    const float* ew    = (const float*)d_in[2];
    const int*   batch = (const int*)  d_in[3];
    const float* W1    = (const float*)d_in[4];
    const float* b1    = (const float*)d_in[5];
    const float* W2    = (const float*)d_in[6];
    const float* b2    = (const float*)d_in[7];
    const float* Wc    = (const float*)d_in[8];
    const float* bc    = (const float*)d_in[9];
    float* out = (float*)d_out;

    const int* row = ei;
    const int* col = ei + N_EDGES;

    // workspace (~78 MB): recs | xlA | xlB | csr | rowptr | dis | bsum | boff | sval
    // H aliases csr (dead before degcsr writes csr).
    int2*     recs   = (int2*)d_ws;                              // E int2 = 25.6 MB
    ushort_t* xlA    = (ushort_t*)(recs + N_EDGES);              // N*HID bf16
    ushort_t* xlB    = xlA + (size_t)N_NODES * HID;              // N*HID bf16
    int2*     csr    = (int2*)(xlB + (size_t)N_NODES * HID);     // E int2
    int*      rowptr = (int*)(csr + N_EDGES);                    // N_PAD
    float*    dis    = (float*)(rowptr + N_PAD);                 // N_PAD
    int*      bsum   = (int*)(dis + N_PAD);                      // 512
    int*      boff   = bsum + 512;                               // 512
    float*    sval   = (float*)(boff + 512);                     // N_PAD
    int*      H      = (int*)csr;                                // NB*NBLK ints = 401 KB

    bhist_gemm1_kernel<<<NBLK + G1BLK, 256, 0, stream>>>(col, H, x, W1, xlA);
    scan1_kernel    <<<NB,   256, 0, stream>>>(H, bsum);
    bscatter_kernel <<<NBLK, 256, 0, stream>>>(row, col, ew, H, bsum, boff, recs);
    degcsr_kernel   <<<NB,   256, 0, stream>>>(recs, boff, dis, rowptr, csr, xlA);
    gather_gemm2_kernel<<<N_NODES / 16, 256, 0, stream>>>(csr, rowptr, dis, xlA, W2, b1, xlB);
    gather_pool_kernel <<<N_NODES / 16, 256, 0, stream>>>(csr, rowptr, dis, xlB, b2, Wc, sval);
    final_out_kernel<<<N_GRAPHS, 256, 0, stream>>>(sval, batch, bc, out);
}

// Round 2
// 369.001 us; speedup vs baseline: 1.1913x; 1.0754x over previous
//
#include <hip/hip_runtime.h>

#define N_NODES 100000
#define N_PAD   100352        // 392*256
#define N_EDGES 3200000
#define IN_DIM  128
#define HID     64
#define N_GRAPHS 256
#define NB      392           // buckets of 256 dest nodes each
#define NBLK    256           // hist/scatter blocks
#define EPB     (N_EDGES / NBLK)   // 12500
#define G1ROWS  32                 // rows per gemm1 block
#define G1BLK   (N_NODES / G1ROWS) // 3125 gemm1 blocks

typedef unsigned short ushort_t;
typedef unsigned int   uint_t;

// bf16 helpers: storage-only compression of the gathered operand
__device__ __forceinline__ ushort_t f2bf(float v) {          // round-to-nearest-even
    uint_t b = __float_as_uint(v);
    b += 0x7fffu + ((b >> 16) & 1u);
    return (ushort_t)(b >> 16);
}
__device__ __forceinline__ void bf2f2(uint_t u, float& lo, float& hi) {
    lo = __uint_as_float(u << 16);
    hi = __uint_as_float(u & 0xffff0000u);
}
// 16B load -> 8 floats
__device__ __forceinline__ void ld_bf16x8(const ushort_t* p, float4& a, float4& b) {
    uint4 u = *(const uint4*)p;
    bf2f2(u.x, a.x, a.y); bf2f2(u.y, a.z, a.w);
    bf2f2(u.z, b.x, b.y); bf2f2(u.w, b.z, b.w);
}
// unpack a loaded uint4 (8 bf16) and FMA into the accumulators with weight w
__device__ __forceinline__ void fma8(float4& a0, float4& a1, const uint4& u, float w) {
    float lo, hi;
    bf2f2(u.x, lo, hi); a0.x += lo * w; a0.y += hi * w;
    bf2f2(u.y, lo, hi); a0.z += lo * w; a0.w += hi * w;
    bf2f2(u.z, lo, hi); a1.x += lo * w; a1.y += hi * w;
    bf2f2(u.w, lo, hi); a1.z += lo * w; a1.w += hi * w;
}

// ---------- phase 1 (fused): bucket histogram (blocks 0..NBLK-1) + gemm1 (rest) ----------
// gemm1: 32 rows/block, each wave computes 8 rows x 64 cols with acc[8] —
// one sW wave-read amortized over 8 FMAs (was 1:1 -> LDS-pipe-bound at 90us).
__global__ __launch_bounds__(256) void bhist_gemm1_kernel(
        const int* __restrict__ col, int* __restrict__ H,
        const float* __restrict__ x, const float* __restrict__ W1,
        ushort_t* __restrict__ xl) {
    __shared__ float sW[IN_DIM * HID];     // 32 KB (hist aliases h into here)
    __shared__ float sx[G1ROWS][IN_DIM];   // 16 KB
    int tid = threadIdx.x;
    if (blockIdx.x < NBLK) {
        int (*h)[NB] = (int (*)[NB])sW;    // hist blocks never use sW as floats
        for (int i = tid; i < NB; i += 256) { h[0][i] = 0; h[1][i] = 0; }
        __syncthreads();
        const int4* col4 = (const int4*)col;
        int base4 = blockIdx.x * (EPB / 4);
        int sel = tid & 1;
        for (int j = tid; j < EPB / 4; j += 256) {
            int4 c = col4[base4 + j];
            atomicAdd(&h[sel][c.x >> 8], 1);
            atomicAdd(&h[sel][c.y >> 8], 1);
            atomicAdd(&h[sel][c.z >> 8], 1);
            atomicAdd(&h[sel][c.w >> 8], 1);
        }
        __syncthreads();
        for (int i = tid; i < NB; i += 256) H[i * NBLK + blockIdx.x] = h[0][i] + h[1][i];
    } else {
        int bid = blockIdx.x - NBLK;
        const float4* W4  = (const float4*)W1;
        float4*       sW4 = (float4*)sW;
        #pragma unroll
        for (int i = 0; i < 8; ++i) sW4[tid + 256 * i] = W4[tid + 256 * i];
        int r0 = bid * G1ROWS;
        const float4* x4  = (const float4*)(x + (size_t)r0 * IN_DIM);
        float4*       sx4 = (float4*)&sx[0][0];
        #pragma unroll
        for (int i = 0; i < 4; ++i) sx4[tid + 256 * i] = x4[tid + 256 * i];  // 32 rows
        __syncthreads();
        int c  = tid & 63;
        int rb = (tid >> 6) * 8;           // wave's 8 rows
        float acc0 = 0.f, acc1 = 0.f, acc2 = 0.f, acc3 = 0.f;
        float acc4 = 0.f, acc5 = 0.f, acc6 = 0.f, acc7 = 0.f;
        #pragma unroll 4
        for (int k4 = 0; k4 < IN_DIM; k4 += 4) {
            float4 x0 = *(const float4*)&sx[rb + 0][k4];   // broadcast b128 reads
            float4 x1 = *(const float4*)&sx[rb + 1][k4];
            float4 x2 = *(const float4*)&sx[rb + 2][k4];
            float4 x3 = *(const float4*)&sx[rb + 3][k4];
            float4 x4r = *(const float4*)&sx[rb + 4][k4];
            float4 x5 = *(const float4*)&sx[rb + 5][k4];
            float4 x6 = *(const float4*)&sx[rb + 6][k4];
            float4 x7 = *(const float4*)&sx[rb + 7][k4];
            #pragma unroll
            for (int kk = 0; kk < 4; ++kk) {
                float wk = sW[(k4 + kk) * HID + c];
                acc0 += ((const float*)&x0)[kk] * wk;
                acc1 += ((const float*)&x1)[kk] * wk;
                acc2 += ((const float*)&x2)[kk] * wk;
                acc3 += ((const float*)&x3)[kk] * wk;
                acc4 += ((const float*)&x4r)[kk] * wk;
                acc5 += ((const float*)&x5)[kk] * wk;
                acc6 += ((const float*)&x6)[kk] * wk;
                acc7 += ((const float*)&x7)[kk] * wk;
            }
        }
        ushort_t* o = xl + (size_t)(r0 + rb) * HID + c;
        o[0 * HID] = f2bf(acc0);
        o[1 * HID] = f2bf(acc1);
        o[2 * HID] = f2bf(acc2);
        o[3 * HID] = f2bf(acc3);
        o[4 * HID] = f2bf(acc4);
        o[5 * HID] = f2bf(acc5);
        o[6 * HID] = f2bf(acc6);
        o[7 * HID] = f2bf(acc7);
    }
}

// ---------- phase 2: exclusive scan of H (NB*NBLK, bucket-major) ----------
__global__ __launch_bounds__(256) void scan1_kernel(int* H, int* __restrict__ bsum) {
    __shared__ int s[256];
    int i = blockIdx.x * 256 + threadIdx.x;   // blockIdx.x == bucket (NBLK==256)
    int v = H[i];
    s[threadIdx.x] = v;
    __syncthreads();
    #pragma unroll
    for (int off = 1; off < 256; off <<= 1) {
        int t = (threadIdx.x >= off) ? s[threadIdx.x - off] : 0;
        __syncthreads();
        s[threadIdx.x] += t;
        __syncthreads();
    }
    H[i] = s[threadIdx.x] - v;                           // exclusive within bucket
    if (threadIdx.x == 255) bsum[blockIdx.x] = s[255];   // bucket total
}

// ---------- phase 3: LDS-staged scatter — bucket-sort in LDS, coalesced burst out ----------
// rec = (row | local<<17, ew); local = col & 255 (8 bits), row < 2^17
__global__ __launch_bounds__(256) void bscatter_kernel(const int* __restrict__ row,
                                                       const int* __restrict__ col,
                                                       const float* __restrict__ ew,
                                                       const int* __restrict__ H,
                                                       const int* __restrict__ bsum,
                                                       int* __restrict__ boff,
                                                       int2* __restrict__ recs) {
    __shared__ int2 lrec[EPB];        // 100 KB: the block's records, bucket-sorted
    __shared__ int  lofs[NB];
    __shared__ int  hcnt[NB];
    __shared__ int  gofs[NB];
    __shared__ int  cur[NB];
    __shared__ int  s[256];
    __shared__ int  carry;
    int tid = threadIdx.x, blk = blockIdx.x;
    if (tid == 0) carry = 0;
    __syncthreads();
    for (int c = 0; c < 2; ++c) {                 // 2*256 >= NB
        int i = c * 256 + tid;
        int v = (i < NB) ? bsum[i] : 0;
        s[tid] = v;
        __syncthreads();
        #pragma unroll
        for (int off = 1; off < 256; off <<= 1) {
            int t = (tid >= off) ? s[tid - off] : 0;
            __syncthreads();
            s[tid] += t;
            __syncthreads();
        }
        if (i < NB) {
            int tb = s[tid] - v + carry;          // bucket start in recs
            int ex = H[i * NBLK + blk];
            gofs[i] = tb + ex;
            hcnt[i] = ((blk < NBLK - 1) ? H[i * NBLK + blk + 1] : v) - ex;
            if (blk == 0) boff[i] = tb;
        }
        __syncthreads();
        if (tid == 0) carry += s[255];
        __syncthreads();
    }
    if (tid == 0) carry = 0;
    __syncthreads();
    for (int c = 0; c < 2; ++c) {
        int i = c * 256 + tid;
        int v = (i < NB) ? hcnt[i] : 0;
        s[tid] = v;
        __syncthreads();
        #pragma unroll
        for (int off = 1; off < 256; off <<= 1) {
            int t = (tid >= off) ? s[tid - off] : 0;
            __syncthreads();
            s[tid] += t;
            __syncthreads();
        }
        if (i < NB) { int l = s[tid] - v + carry; lofs[i] = l; cur[i] = l; }
        __syncthreads();
        if (tid == 0) carry += s[255];
        __syncthreads();
    }
    const int4*   row4 = (const int4*)row;
    const int4*   col4 = (const int4*)col;
    const float4* ew4  = (const float4*)ew;
    int base4 = blk * (EPB / 4);
    for (int j = tid; j < EPB / 4; j += 256) {
        int4   r4 = row4[base4 + j];
        int4   c4 = col4[base4 + j];
        float4 w4 = ew4[base4 + j];
        int p0 = atomicAdd(&cur[c4.x >> 8], 1);
        lrec[p0] = make_int2(r4.x | ((c4.x & 255) << 17), __float_as_int(w4.x));
        int p1 = atomicAdd(&cur[c4.y >> 8], 1);
        lrec[p1] = make_int2(r4.y | ((c4.y & 255) << 17), __float_as_int(w4.y));
        int p2 = atomicAdd(&cur[c4.z >> 8], 1);
        lrec[p2] = make_int2(r4.z | ((c4.z & 255) << 17), __float_as_int(w4.z));
        int p3 = atomicAdd(&cur[c4.w >> 8], 1);
        lrec[p3] = make_int2(r4.w | ((c4.w & 255) << 17), __float_as_int(w4.w));
    }
    __syncthreads();
    int wv = tid >> 6, lane = tid & 63;
    for (int i = wv; i < NB; i += 4) {
        int cnt = hcnt[i], lo = lofs[i], go = gofs[i];
        for (int k = lane; k < cnt; k += 64)
            recs[go + k] = lrec[lo + k];
    }
}

// ---------- phase 3.5 (fused): recs pass -> deg+cnt -> dis/rowptr -> csr permutation
// scatter (L2-warm) -> yl scale tail. All block-local after R15's factorization.
__global__ __launch_bounds__(256) void degcsr_kernel(const int2* __restrict__ recs,
                                                     const int* __restrict__ boff,
                                                     float* __restrict__ dis,
                                                     int* __restrict__ rowptr,
                                                     int2* __restrict__ csr,
                                                     ushort_t* xl) {
    __shared__ int   cnt[256];
    __shared__ float degf[256];
    __shared__ int   sscan[256];
    __shared__ int   cur[256];
    int b = blockIdx.x, tid = threadIdx.x;
    cnt[tid] = 0; degf[tid] = 0.f;
    __syncthreads();
    int s = boff[b], e = (b + 1 < NB) ? boff[b + 1] : N_EDGES;
    for (int j = s + tid; j < e; j += 256) {
        int2 r = recs[j];
        int cl = (r.x >> 17) & 255;
        atomicAdd(&cnt[cl], 1);
        atomicAdd(&degf[cl], __int_as_float(r.y));
    }
    __syncthreads();
    int c = cnt[tid];
    sscan[tid] = c;
    __syncthreads();
    #pragma unroll
    for (int off = 1; off < 256; off <<= 1) {
        int t = (tid >= off) ? sscan[tid - off] : 0;
        __syncthreads();
        sscan[tid] += t;
        __syncthreads();
    }
    int rp = s + sscan[tid] - c;                  // exclusive; pad nodes get == e
    rowptr[b * 256 + tid] = rp;
    cur[tid] = rp;
    float d = 1.0f / sqrtf(fmaxf(1.0f + degf[tid], 1e-30f));
    dis[b * 256 + tid] = d;
    __syncthreads();
    degf[tid] = d;                                // reuse as dis cache for the tail
    __syncthreads();
    // csr permutation scatter (bucket's recs are L2-warm from pass 1)
    for (int j = s + tid; j < e; j += 256) {
        int2 r = recs[j];
        int cl = (r.x >> 17) & 255;
        int pos = atomicAdd(&cur[cl], 1);
        csr[pos] = r;                             // gather masks the local bits
    }
    // scale tail: yl = dis * xl for this bucket's 256 rows (coalesced uint4)
    int n0 = b * 256;
    for (int i = tid; i < 256 * 8; i += 256) {    // 8 uint4 chunks per 64-ch row
        int r = i >> 3;
        int n = n0 + r;
        if (n >= N_NODES) break;                  // trailing pad rows
        uint4* p = (uint4*)(xl + (size_t)n * HID) + (i & 7);
        float d2 = degf[r];
        uint4 u = *p;
        float lo, hi;
        uint_t w0, w1, w2, w3;
        bf2f2(u.x, lo, hi); w0 = f2bf(lo * d2) | ((uint_t)f2bf(hi * d2) << 16);
        bf2f2(u.y, lo, hi); w1 = f2bf(lo * d2) | ((uint_t)f2bf(hi * d2) << 16);
        bf2f2(u.z, lo, hi); w2 = f2bf(lo * d2) | ((uint_t)f2bf(hi * d2) << 16);
        bf2f2(u.w, lo, hi); w3 = f2bf(lo * d2) | ((uint_t)f2bf(hi * d2) << 16);
        *p = make_uint4(w0, w1, w2, w3);
    }
}

// ---------- gather core: 16 lanes/node (2 groups of 8), 8 edges in flight/group ----------
// computes yl[n] + sum ew*yl[r] for the lane's 8 channels; includes the single-level
// cross-group reduce (valid in lanes with (lane&15)<8). Caller multiplies by dis[n].
__device__ __forceinline__ void gather_row16(const int2* __restrict__ csr,
                                             const ushort_t* __restrict__ xl,
                                             int base, int end, int n,
                                             int g, int c0,
                                             float4& a0, float4& a1) {
    a0 = make_float4(0.f, 0.f, 0.f, 0.f);
    a1 = make_float4(0.f, 0.f, 0.f, 0.f);
    if (g == 0) {
        ld_bf16x8(xl + (size_t)n * HID + c0, a0, a1);   // self-loop, weight 1
    }
    int j = base + g;
    for (; j + 14 < end; j += 16) {                      // 8 edges in flight
        int2 e0 = csr[j];
        int2 e1 = csr[j + 2];
        int2 e2 = csr[j + 4];
        int2 e3 = csr[j + 6];
        int2 e4 = csr[j + 8];
        int2 e5 = csr[j + 10];
        int2 e6 = csr[j + 12];
        int2 e7 = csr[j + 14];
        uint4 u0 = *(const uint4*)(xl + (size_t)(e0.x & 0x1FFFF) * HID + c0);
        uint4 u1 = *(const uint4*)(xl + (size_t)(e1.x & 0x1FFFF) * HID + c0);
        uint4 u2 = *(const uint4*)(xl + (size_t)(e2.x & 0x1FFFF) * HID + c0);
        uint4 u3 = *(const uint4*)(xl + (size_t)(e3.x & 0x1FFFF) * HID + c0);
        uint4 u4 = *(const uint4*)(xl + (size_t)(e4.x & 0x1FFFF) * HID + c0);
        uint4 u5 = *(const uint4*)(xl + (size_t)(e5.x & 0x1FFFF) * HID + c0);
        uint4 u6 = *(const uint4*)(xl + (size_t)(e6.x & 0x1FFFF) * HID + c0);
        uint4 u7 = *(const uint4*)(xl + (size_t)(e7.x & 0x1FFFF) * HID + c0);
        fma8(a0, a1, u0, __int_as_float(e0.y));
        fma8(a0, a1, u1, __int_as_float(e1.y));
        fma8(a0, a1, u2, __int_as_float(e2.y));
        fma8(a0, a1, u3, __int_as_float(e3.y));
        fma8(a0, a1, u4, __int_as_float(e4.y));
        fma8(a0, a1, u5, __int_as_float(e5.y));
        fma8(a0, a1, u6, __int_as_float(e6.y));
        fma8(a0, a1, u7, __int_as_float(e7.y));
    }
    for (; j + 6 < end; j += 8) {                        // 4 edges in flight
        int2 e0 = csr[j];
        int2 e1 = csr[j + 2];
        int2 e2 = csr[j + 4];
        int2 e3 = csr[j + 6];
        uint4 u0 = *(const uint4*)(xl + (size_t)(e0.x & 0x1FFFF) * HID + c0);
        uint4 u1 = *(const uint4*)(xl + (size_t)(e1.x & 0x1FFFF) * HID + c0);
        uint4 u2 = *(const uint4*)(xl + (size_t)(e2.x & 0x1FFFF) * HID + c0);
        uint4 u3 = *(const uint4*)(xl + (size_t)(e3.x & 0x1FFFF) * HID + c0);
        fma8(a0, a1, u0, __int_as_float(e0.y));
        fma8(a0, a1, u1, __int_as_float(e1.y));
        fma8(a0, a1, u2, __int_as_float(e2.y));
        fma8(a0, a1, u3, __int_as_float(e3.y));
    }
    for (; j < end; j += 2) {                            // singles
        int2 e0 = csr[j];
        uint4 u0 = *(const uint4*)(xl + (size_t)(e0.x & 0x1FFFF) * HID + c0);
        fma8(a0, a1, u0, __int_as_float(e0.y));
    }
    // single-level reduce: combine the two 8-lane groups of this node
    a0.x += __shfl_down(a0.x, 8, 64); a0.y += __shfl_down(a0.y, 8, 64);
    a0.z += __shfl_down(a0.z, 8, 64); a0.w += __shfl_down(a0.w, 8, 64);
    a1.x += __shfl_down(a1.x, 8, 64); a1.y += __shfl_down(a1.y, 8, 64);
    a1.z += __shfl_down(a1.z, 8, 64); a1.w += __shfl_down(a1.w, 8, 64);
}

// ---------- fused gather1 + gemm2: yl2 = dis * (relu(dis*(...) + b1) @ W2) ----------
// 16 nodes per block (4 per wave, 16 lanes each).
__global__ __launch_bounds__(256) void gather_gemm2_kernel(
        const int2* __restrict__ csr, const int* __restrict__ rowptr,
        const float* __restrict__ dis, const ushort_t* __restrict__ xl,
        const float* __restrict__ W2, const float* __restrict__ b1,
        ushort_t* __restrict__ xl2) {
    __shared__ float sW[HID * HID];     // 16 KB
    __shared__ float sh[16][HID + 4];   // pad 68: breaks row-alias on ds_write_b128
    int tid = threadIdx.x;
    const float4* W4  = (const float4*)W2;
    float4*       sW4 = (float4*)sW;
    #pragma unroll
    for (int i = 0; i < 4; ++i) sW4[tid + 256 * i] = W4[tid + 256 * i];

    int n0   = blockIdx.x * 16;
    int wv   = tid >> 6;
    int lane = tid & 63;
    int lr   = wv * 4 + (lane >> 4);     // local row 0..15
    int n    = n0 + lr;
    int g    = (lane >> 3) & 1;
    int c0   = (lane & 7) << 3;
    int base = rowptr[n], end = rowptr[n + 1];
    float d  = dis[n];
    float4 a0, a1;
    gather_row16(csr, xl, base, end, n, g, c0, a0, a1);
    if (g == 0) {
        // h = relu(dis[col]*agg + b1), stored directly (no second pass)
        float4 bb0 = *(const float4*)(b1 + c0);
        float4 bb1 = *(const float4*)(b1 + c0 + 4);
        float4 h0 = make_float4(fmaxf(a0.x * d + bb0.x, 0.f), fmaxf(a0.y * d + bb0.y, 0.f),
                                fmaxf(a0.z * d + bb0.z, 0.f), fmaxf(a0.w * d + bb0.w, 0.f));
        float4 h1 = make_float4(fmaxf(a1.x * d + bb1.x, 0.f), fmaxf(a1.y * d + bb1.y, 0.f),
                                fmaxf(a1.z * d + bb1.z, 0.f), fmaxf(a1.w * d + bb1.w, 0.f));
        *(float4*)(&sh[lr][c0])     = h0;
        *(float4*)(&sh[lr][c0 + 4]) = h1;
    }
    __syncthreads();
    // gemm2: each thread computes 4 rows x 1 col; sW value reused 4x per read
    int cc = tid & 63, rq = tid >> 6;
    float acc0 = 0.f, acc1 = 0.f, acc2 = 0.f, acc3 = 0.f;
    #pragma unroll 8
    for (int k = 0; k < HID; ++k) {
        float wk = sW[k * HID + cc];
        acc0 += sh[rq * 4 + 0][k] * wk;
        acc1 += sh[rq * 4 + 1][k] * wk;
        acc2 += sh[rq * 4 + 2][k] * wk;
        acc3 += sh[rq * 4 + 3][k] * wk;
    }
    xl2[(size_t)(n0 + rq * 4 + 0) * HID + cc] = f2bf(acc0 * dis[n0 + rq * 4 + 0]);
    xl2[(size_t)(n0 + rq * 4 + 1) * HID + cc] = f2bf(acc1 * dis[n0 + rq * 4 + 1]);
    xl2[(size_t)(n0 + rq * 4 + 2) * HID + cc] = f2bf(acc2 * dis[n0 + rq * 4 + 2]);
    xl2[(size_t)(n0 + rq * 4 + 3) * HID + cc] = f2bf(acc3 * dis[n0 + rq * 4 + 3]);
}

// ---------- fused gather2 + pool partial: sval[n] = relu(dis*(...)+b2) . Wc ----------
__global__ __launch_bounds__(256) void gather_pool_kernel(
        const int2* __restrict__ csr, const int* __restrict__ rowptr,
        const float* __restrict__ dis, const ushort_t* __restrict__ xl,
        const float* __restrict__ b2, const float* __restrict__ Wc,
        float* __restrict__ sval) {
    int tid  = threadIdx.x;
    int n    = (blockIdx.x * 256 + tid) >> 4;           // grid 6250 exact
    int lane = tid & 63;
    int g    = (lane >> 3) & 1;
    int c0   = (lane & 7) << 3;
    int base = rowptr[n], end = rowptr[n + 1];
    float d  = dis[n];
    float4 a0, a1;
    gather_row16(csr, xl, base, end, n, g, c0, a0, a1);
    // all lanes compute (g==1 lanes produce garbage that is never read)
    float4 bb0 = *(const float4*)(b2 + c0);
    float4 bb1 = *(const float4*)(b2 + c0 + 4);
    float4 wc0 = *(const float4*)(Wc + c0);
    float4 wc1 = *(const float4*)(Wc + c0 + 4);
    float s = fmaxf(a0.x * d + bb0.x, 0.f) * wc0.x + fmaxf(a0.y * d + bb0.y, 0.f) * wc0.y
            + fmaxf(a0.z * d + bb0.z, 0.f) * wc0.z + fmaxf(a0.w * d + bb0.w, 0.f) * wc0.w
            + fmaxf(a1.x * d + bb1.x, 0.f) * wc1.x + fmaxf(a1.y * d + bb1.y, 0.f) * wc1.y
            + fmaxf(a1.z * d + bb1.z, 0.f) * wc1.z + fmaxf(a1.w * d + bb1.w, 0.f) * wc1.w;
    s += __shfl_down(s, 4, 64);
    s += __shfl_down(s, 2, 64);
    s += __shfl_down(s, 1, 64);
    if ((lane & 15) == 0) sval[n] = s;
}

// ---------- final: out[g] = mean(sval over graph range) + bc ----------
__global__ __launch_bounds__(256) void final_out_kernel(const float* __restrict__ sval,
                                                        const int* __restrict__ batch,
                                                        const float* __restrict__ bc,
                                                        float* __restrict__ out) {
    __shared__ float s[256];
    int g = blockIdx.x;   // grid N_GRAPHS
    int lo = 0, hi = N_NODES;
    while (lo < hi) { int m = (lo + hi) >> 1; if (batch[m] < g) lo = m + 1; else hi = m; }
    int start = lo;
    hi = N_NODES;
    while (lo < hi) { int m = (lo + hi) >> 1; if (batch[m] < g + 1) lo = m + 1; else hi = m; }
    int end = lo;
    float acc = 0.f;
    for (int i = start + threadIdx.x; i < end; i += 256) acc += sval[i];
    s[threadIdx.x] = acc;
    __syncthreads();
    #pragma unroll
    for (int off = 128; off > 0; off >>= 1) {
        if (threadIdx.x < off) s[threadIdx.x] += s[threadIdx.x + off];
        __syncthreads();
    }
    if (threadIdx.x == 0)
        out[g] = s[0] / fmaxf((float)(end - start), 1.0f) + bc[0];
}

extern "C" void kernel_launch(void* const* d_in, const int* in_sizes, int n_in,
                              void* d_out, int out_size, void* d_ws, size_t ws_size,
                              hipStream_t stream) {
    const float* x     = (const float*)d_in[0];
    const int*   ei    = (const int*)  d_in[1];
    const float* ew    = (const float*)d_in[2];
    const int*   batch = (const int*)  d_in[3];
    const float* W1    = (const float*)d_in[4];
    const float* b1    = (const float*)d_in[5];
    const float* W2    = (const float*)d_in[6];
    const float* b2    = (const float*)d_in[7];
    const float* Wc    = (const float*)d_in[8];
    const float* bc    = (const float*)d_in[9];
    float* out = (float*)d_out;

    const int* row = ei;
    const int* col = ei + N_EDGES;

    // workspace (~78 MB): recs | xlA | xlB | csr | rowptr | dis | bsum | boff | sval
    // H aliases csr (dead before degcsr writes csr).
    int2*     recs   = (int2*)d_ws;                              // E int2 = 25.6 MB
    ushort_t* xlA    = (ushort_t*)(recs + N_EDGES);              // N*HID bf16
    ushort_t* xlB    = xlA + (size_t)N_NODES * HID;              // N*HID bf16
    int2*     csr    = (int2*)(xlB + (size_t)N_NODES * HID);     // E int2
    int*      rowptr = (int*)(csr + N_EDGES);                    // N_PAD
    float*    dis    = (float*)(rowptr + N_PAD);                 // N_PAD
    int*      bsum   = (int*)(dis + N_PAD);                      // 512
    int*      boff   = bsum + 512;                               // 512
    float*    sval   = (float*)(boff + 512);                     // N_PAD
    int*      H      = (int*)csr;                                // NB*NBLK ints = 401 KB

    bhist_gemm1_kernel<<<NBLK + G1BLK, 256, 0, stream>>>(col, H, x, W1, xlA);
    scan1_kernel    <<<NB,   256, 0, stream>>>(H, bsum);
    bscatter_kernel <<<NBLK, 256, 0, stream>>>(row, col, ew, H, bsum, boff, recs);
    degcsr_kernel   <<<NB,   256, 0, stream>>>(recs, boff, dis, rowptr, csr, xlA);
    gather_gemm2_kernel<<<N_NODES / 16, 256, 0, stream>>>(csr, rowptr, dis, xlA, W2, b1, xlB);
    gather_pool_kernel <<<N_NODES / 16, 256, 0, stream>>>(csr, rowptr, dis, xlB, b2, Wc, sval);
    final_out_kernel<<<N_GRAPHS, 256, 0, stream>>>(sval, batch, bc, out);
}

// Round 3
// 360.547 us; speedup vs baseline: 1.2192x; 1.0234x over previous
//
#include <hip/hip_runtime.h>

#define N_NODES 100000
#define N_PAD   100352        // 392*256
#define N_EDGES 3200000
#define IN_DIM  128
#define HID     64
#define N_GRAPHS 256
#define NB      392           // buckets of 256 dest nodes each
#define NBLK    256           // hist/scatter blocks
#define EPB     (N_EDGES / NBLK)   // 12500
#define G1ROWS  32                 // rows per gemm1 block
#define G1BLK   (N_NODES / G1ROWS) // 3125 gemm1 blocks

typedef unsigned short ushort_t;
typedef unsigned int   uint_t;

// bf16 helpers: storage-only compression of the gathered operand
__device__ __forceinline__ ushort_t f2bf(float v) {          // round-to-nearest-even
    uint_t b = __float_as_uint(v);
    b += 0x7fffu + ((b >> 16) & 1u);
    return (ushort_t)(b >> 16);
}
__device__ __forceinline__ void bf2f2(uint_t u, float& lo, float& hi) {
    lo = __uint_as_float(u << 16);
    hi = __uint_as_float(u & 0xffff0000u);
}
// 16B load -> 8 floats
__device__ __forceinline__ void ld_bf16x8(const ushort_t* p, float4& a, float4& b) {
    uint4 u = *(const uint4*)p;
    bf2f2(u.x, a.x, a.y); bf2f2(u.y, a.z, a.w);
    bf2f2(u.z, b.x, b.y); bf2f2(u.w, b.z, b.w);
}
// unpack a loaded uint4 (8 bf16) and FMA into the accumulators with weight w
__device__ __forceinline__ void fma8(float4& a0, float4& a1, const uint4& u, float w) {
    float lo, hi;
    bf2f2(u.x, lo, hi); a0.x += lo * w; a0.y += hi * w;
    bf2f2(u.y, lo, hi); a0.z += lo * w; a0.w += hi * w;
    bf2f2(u.z, lo, hi); a1.x += lo * w; a1.y += hi * w;
    bf2f2(u.w, lo, hi); a1.z += lo * w; a1.w += hi * w;
}
// clamped edge-record load: pad slots re-read the last valid record with weight 0
__device__ __forceinline__ int2 ldrec(const int2* __restrict__ csr, int last, int idx) {
    int2 r = csr[idx <= last ? idx : last];
    if (idx > last) r.y = 0;
    return r;
}

// ---------- phase 1 (fused): bucket histogram (blocks 0..NBLK-1) + gemm1 (rest) ----------
// gemm1: 32 rows/block, each wave computes 8 rows x 64 cols with acc[8] —
// one sW wave-read amortized over 8 FMAs (was 1:1 -> LDS-pipe-bound at 90us).
__global__ __launch_bounds__(256) void bhist_gemm1_kernel(
        const int* __restrict__ col, int* __restrict__ H,
        const float* __restrict__ x, const float* __restrict__ W1,
        ushort_t* __restrict__ xl) {
    __shared__ float sW[IN_DIM * HID];     // 32 KB (hist aliases h into here)
    __shared__ float sx[G1ROWS][IN_DIM];   // 16 KB
    int tid = threadIdx.x;
    if (blockIdx.x < NBLK) {
        int (*h)[NB] = (int (*)[NB])sW;    // hist blocks never use sW as floats
        for (int i = tid; i < NB; i += 256) { h[0][i] = 0; h[1][i] = 0; }
        __syncthreads();
        const int4* col4 = (const int4*)col;
        int base4 = blockIdx.x * (EPB / 4);
        int sel = tid & 1;
        for (int j = tid; j < EPB / 4; j += 256) {
            int4 c = col4[base4 + j];
            atomicAdd(&h[sel][c.x >> 8], 1);
            atomicAdd(&h[sel][c.y >> 8], 1);
            atomicAdd(&h[sel][c.z >> 8], 1);
            atomicAdd(&h[sel][c.w >> 8], 1);
        }
        __syncthreads();
        for (int i = tid; i < NB; i += 256) H[i * NBLK + blockIdx.x] = h[0][i] + h[1][i];
    } else {
        int bid = blockIdx.x - NBLK;
        const float4* W4  = (const float4*)W1;
        float4*       sW4 = (float4*)sW;
        #pragma unroll
        for (int i = 0; i < 8; ++i) sW4[tid + 256 * i] = W4[tid + 256 * i];
        int r0 = bid * G1ROWS;
        const float4* x4  = (const float4*)(x + (size_t)r0 * IN_DIM);
        float4*       sx4 = (float4*)&sx[0][0];
        #pragma unroll
        for (int i = 0; i < 4; ++i) sx4[tid + 256 * i] = x4[tid + 256 * i];  // 32 rows
        __syncthreads();
        int c  = tid & 63;
        int rb = (tid >> 6) * 8;           // wave's 8 rows
        float acc0 = 0.f, acc1 = 0.f, acc2 = 0.f, acc3 = 0.f;
        float acc4 = 0.f, acc5 = 0.f, acc6 = 0.f, acc7 = 0.f;
        #pragma unroll 4
        for (int k4 = 0; k4 < IN_DIM; k4 += 4) {
            float4 x0 = *(const float4*)&sx[rb + 0][k4];   // broadcast b128 reads
            float4 x1 = *(const float4*)&sx[rb + 1][k4];
            float4 x2 = *(const float4*)&sx[rb + 2][k4];
            float4 x3 = *(const float4*)&sx[rb + 3][k4];
            float4 x4r = *(const float4*)&sx[rb + 4][k4];
            float4 x5 = *(const float4*)&sx[rb + 5][k4];
            float4 x6 = *(const float4*)&sx[rb + 6][k4];
            float4 x7 = *(const float4*)&sx[rb + 7][k4];
            #pragma unroll
            for (int kk = 0; kk < 4; ++kk) {
                float wk = sW[(k4 + kk) * HID + c];
                acc0 += ((const float*)&x0)[kk] * wk;
                acc1 += ((const float*)&x1)[kk] * wk;
                acc2 += ((const float*)&x2)[kk] * wk;
                acc3 += ((const float*)&x3)[kk] * wk;
                acc4 += ((const float*)&x4r)[kk] * wk;
                acc5 += ((const float*)&x5)[kk] * wk;
                acc6 += ((const float*)&x6)[kk] * wk;
                acc7 += ((const float*)&x7)[kk] * wk;
            }
        }
        ushort_t* o = xl + (size_t)(r0 + rb) * HID + c;
        o[0 * HID] = f2bf(acc0);
        o[1 * HID] = f2bf(acc1);
        o[2 * HID] = f2bf(acc2);
        o[3 * HID] = f2bf(acc3);
        o[4 * HID] = f2bf(acc4);
        o[5 * HID] = f2bf(acc5);
        o[6 * HID] = f2bf(acc6);
        o[7 * HID] = f2bf(acc7);
    }
}

// ---------- phase 2: exclusive scan of H (NB*NBLK, bucket-major) ----------
__global__ __launch_bounds__(256) void scan1_kernel(int* H, int* __restrict__ bsum) {
    __shared__ int s[256];
    int i = blockIdx.x * 256 + threadIdx.x;   // blockIdx.x == bucket (NBLK==256)
    int v = H[i];
    s[threadIdx.x] = v;
    __syncthreads();
    #pragma unroll
    for (int off = 1; off < 256; off <<= 1) {
        int t = (threadIdx.x >= off) ? s[threadIdx.x - off] : 0;
        __syncthreads();
        s[threadIdx.x] += t;
        __syncthreads();
    }
    H[i] = s[threadIdx.x] - v;                           // exclusive within bucket
    if (threadIdx.x == 255) bsum[blockIdx.x] = s[255];   // bucket total
}

// ---------- phase 3: LDS-staged scatter — bucket-sort in LDS, coalesced burst out ----------
// rec = (row | local<<17, ew); local = col & 255 (8 bits), row < 2^17
__global__ __launch_bounds__(256) void bscatter_kernel(const int* __restrict__ row,
                                                       const int* __restrict__ col,
                                                       const float* __restrict__ ew,
                                                       const int* __restrict__ H,
                                                       const int* __restrict__ bsum,
                                                       int* __restrict__ boff,
                                                       int2* __restrict__ recs) {
    __shared__ int2 lrec[EPB];        // 100 KB: the block's records, bucket-sorted
    __shared__ int  lofs[NB];
    __shared__ int  hcnt[NB];
    __shared__ int  gofs[NB];
    __shared__ int  cur[NB];
    __shared__ int  s[256];
    __shared__ int  carry;
    int tid = threadIdx.x, blk = blockIdx.x;
    if (tid == 0) carry = 0;
    __syncthreads();
    for (int c = 0; c < 2; ++c) {                 // 2*256 >= NB
        int i = c * 256 + tid;
        int v = (i < NB) ? bsum[i] : 0;
        s[tid] = v;
        __syncthreads();
        #pragma unroll
        for (int off = 1; off < 256; off <<= 1) {
            int t = (tid >= off) ? s[tid - off] : 0;
            __syncthreads();
            s[tid] += t;
            __syncthreads();
        }
        if (i < NB) {
            int tb = s[tid] - v + carry;          // bucket start in recs
            int ex = H[i * NBLK + blk];
            gofs[i] = tb + ex;
            hcnt[i] = ((blk < NBLK - 1) ? H[i * NBLK + blk + 1] : v) - ex;
            if (blk == 0) boff[i] = tb;
        }
        __syncthreads();
        if (tid == 0) carry += s[255];
        __syncthreads();
    }
    if (tid == 0) carry = 0;
    __syncthreads();
    for (int c = 0; c < 2; ++c) {
        int i = c * 256 + tid;
        int v = (i < NB) ? hcnt[i] : 0;
        s[tid] = v;
        __syncthreads();
        #pragma unroll
        for (int off = 1; off < 256; off <<= 1) {
            int t = (tid >= off) ? s[tid - off] : 0;
            __syncthreads();
            s[tid] += t;
            __syncthreads();
        }
        if (i < NB) { int l = s[tid] - v + carry; lofs[i] = l; cur[i] = l; }
        __syncthreads();
        if (tid == 0) carry += s[255];
        __syncthreads();
    }
    const int4*   row4 = (const int4*)row;
    const int4*   col4 = (const int4*)col;
    const float4* ew4  = (const float4*)ew;
    int base4 = blk * (EPB / 4);
    for (int j = tid; j < EPB / 4; j += 256) {
        int4   r4 = row4[base4 + j];
        int4   c4 = col4[base4 + j];
        float4 w4 = ew4[base4 + j];
        int p0 = atomicAdd(&cur[c4.x >> 8], 1);
        lrec[p0] = make_int2(r4.x | ((c4.x & 255) << 17), __float_as_int(w4.x));
        int p1 = atomicAdd(&cur[c4.y >> 8], 1);
        lrec[p1] = make_int2(r4.y | ((c4.y & 255) << 17), __float_as_int(w4.y));
        int p2 = atomicAdd(&cur[c4.z >> 8], 1);
        lrec[p2] = make_int2(r4.z | ((c4.z & 255) << 17), __float_as_int(w4.z));
        int p3 = atomicAdd(&cur[c4.w >> 8], 1);
        lrec[p3] = make_int2(r4.w | ((c4.w & 255) << 17), __float_as_int(w4.w));
    }
    __syncthreads();
    int wv = tid >> 6, lane = tid & 63;
    for (int i = wv; i < NB; i += 4) {
        int cnt = hcnt[i], lo = lofs[i], go = gofs[i];
        for (int k = lane; k < cnt; k += 64)
            recs[go + k] = lrec[lo + k];
    }
}

// ---------- phase 3.5 (fused): recs pass -> deg+cnt -> dis/rowptr -> csr permutation
// scatter (L2-warm) -> yl scale tail. All block-local after R15's factorization.
__global__ __launch_bounds__(256) void degcsr_kernel(const int2* __restrict__ recs,
                                                     const int* __restrict__ boff,
                                                     float* __restrict__ dis,
                                                     int* __restrict__ rowptr,
                                                     int2* __restrict__ csr,
                                                     ushort_t* xl) {
    __shared__ int   cnt[256];
    __shared__ float degf[256];
    __shared__ int   sscan[256];
    __shared__ int   cur[256];
    int b = blockIdx.x, tid = threadIdx.x;
    cnt[tid] = 0; degf[tid] = 0.f;
    __syncthreads();
    int s = boff[b], e = (b + 1 < NB) ? boff[b + 1] : N_EDGES;
    for (int j = s + tid; j < e; j += 256) {
        int2 r = recs[j];
        int cl = (r.x >> 17) & 255;
        atomicAdd(&cnt[cl], 1);
        atomicAdd(&degf[cl], __int_as_float(r.y));
    }
    __syncthreads();
    int c = cnt[tid];
    sscan[tid] = c;
    __syncthreads();
    #pragma unroll
    for (int off = 1; off < 256; off <<= 1) {
        int t = (tid >= off) ? sscan[tid - off] : 0;
        __syncthreads();
        sscan[tid] += t;
        __syncthreads();
    }
    int rp = s + sscan[tid] - c;                  // exclusive; pad nodes get == e
    rowptr[b * 256 + tid] = rp;
    cur[tid] = rp;
    float d = 1.0f / sqrtf(fmaxf(1.0f + degf[tid], 1e-30f));
    dis[b * 256 + tid] = d;
    __syncthreads();
    degf[tid] = d;                                // reuse as dis cache for the tail
    __syncthreads();
    // csr permutation scatter (bucket's recs are L2-warm from pass 1)
    for (int j = s + tid; j < e; j += 256) {
        int2 r = recs[j];
        int cl = (r.x >> 17) & 255;
        int pos = atomicAdd(&cur[cl], 1);
        csr[pos] = r;                             // gather masks the local bits
    }
    // scale tail: yl = dis * xl for this bucket's 256 rows (coalesced uint4)
    int n0 = b * 256;
    for (int i = tid; i < 256 * 8; i += 256) {    // 8 uint4 chunks per 64-ch row
        int r = i >> 3;
        int n = n0 + r;
        if (n >= N_NODES) break;                  // trailing pad rows
        uint4* p = (uint4*)(xl + (size_t)n * HID) + (i & 7);
        float d2 = degf[r];
        uint4 u = *p;
        float lo, hi;
        uint_t w0, w1, w2, w3;
        bf2f2(u.x, lo, hi); w0 = f2bf(lo * d2) | ((uint_t)f2bf(hi * d2) << 16);
        bf2f2(u.y, lo, hi); w1 = f2bf(lo * d2) | ((uint_t)f2bf(hi * d2) << 16);
        bf2f2(u.z, lo, hi); w2 = f2bf(lo * d2) | ((uint_t)f2bf(hi * d2) << 16);
        bf2f2(u.w, lo, hi); w3 = f2bf(lo * d2) | ((uint_t)f2bf(hi * d2) << 16);
        *p = make_uint4(w0, w1, w2, w3);
    }
}

// ---------- gather core: 16 lanes/node (2 groups of 8), contiguous-half edge split,
// 2-deep software pipeline over 4-edge blocks. One coalesced rec load per block
// (lane li&3 holds rec b+li&3, distributed by shfl); rows for block k+1 are in
// flight while block k's FMAs run; recs fetched 2 blocks ahead.
__device__ __forceinline__ void gather_row16(const int2* __restrict__ csr,
                                             const ushort_t* __restrict__ xl,
                                             int base, int end, int n,
                                             int g, int c0, int lane,
                                             float4& a0, float4& a1) {
    a0 = make_float4(0.f, 0.f, 0.f, 0.f);
    a1 = make_float4(0.f, 0.f, 0.f, 0.f);
    if (g == 0) {
        ld_bf16x8(xl + (uint_t)(n * HID + c0), a0, a1);   // self-loop, weight 1
    }
    int tot  = end - base;
    int half = (tot + 1) >> 1;
    int gs   = base + (g ? half : 0);
    int m    = g ? (tot - half) : half;
    if (m > 0) {
        int last = gs + m - 1;
        int li4  = lane & 3;       // rec slot in block (lanes 4-7 mirror 0-3)
        int gb   = lane & 56;      // group base lane
        int nb   = (m + 3) >> 2;   // number of 4-edge blocks

#define BCI(r_, u0_, u1_, u2_, u3_, w0_, w1_, w2_, w3_) do {                     \
        int r0_ = __shfl((r_).x, gb + 0, 64), r1_ = __shfl((r_).x, gb + 1, 64);  \
        int r2_ = __shfl((r_).x, gb + 2, 64), r3_ = __shfl((r_).x, gb + 3, 64);  \
        w0_ = __int_as_float(__shfl((r_).y, gb + 0, 64));                         \
        w1_ = __int_as_float(__shfl((r_).y, gb + 1, 64));                         \
        w2_ = __int_as_float(__shfl((r_).y, gb + 2, 64));                         \
        w3_ = __int_as_float(__shfl((r_).y, gb + 3, 64));                         \
        u0_ = *(const uint4*)(xl + (uint_t)((r0_ & 0x1FFFF) * HID + c0));         \
        u1_ = *(const uint4*)(xl + (uint_t)((r1_ & 0x1FFFF) * HID + c0));         \
        u2_ = *(const uint4*)(xl + (uint_t)((r2_ & 0x1FFFF) * HID + c0));         \
        u3_ = *(const uint4*)(xl + (uint_t)((r3_ & 0x1FFFF) * HID + c0));         \
    } while (0)

        uint4 uA0, uA1, uA2, uA3, uB0, uB1, uB2, uB3;
        float wA0, wA1, wA2, wA3, wB0, wB1, wB2, wB3;
        int2 rA = ldrec(csr, last, gs + li4);
        int2 rB = (nb > 1) ? ldrec(csr, last, gs + 4 + li4) : rA;
        BCI(rA, uA0, uA1, uA2, uA3, wA0, wA1, wA2, wA3);   // block 0 in flight
        int blk = 0;
        while (true) {
            bool hasB  = (blk + 1 < nb);
            bool hasA2 = (blk + 2 < nb);
            if (hasA2) rA = ldrec(csr, last, gs + (blk + 2) * 4 + li4);
            if (hasB) { BCI(rB, uB0, uB1, uB2, uB3, wB0, wB1, wB2, wB3); }
            fma8(a0, a1, uA0, wA0); fma8(a0, a1, uA1, wA1);
            fma8(a0, a1, uA2, wA2); fma8(a0, a1, uA3, wA3);
            if (!hasB) break;
            bool hasB2 = (blk + 3 < nb);
            if (hasB2) rB = ldrec(csr, last, gs + (blk + 3) * 4 + li4);
            if (hasA2) { BCI(rA, uA0, uA1, uA2, uA3, wA0, wA1, wA2, wA3); }
            fma8(a0, a1, uB0, wB0); fma8(a0, a1, uB1, wB1);
            fma8(a0, a1, uB2, wB2); fma8(a0, a1, uB3, wB3);
            if (!hasA2) break;
            blk += 2;
        }
#undef BCI
    }
    // single-level reduce: combine the two 8-lane groups of this node
    a0.x += __shfl_down(a0.x, 8, 64); a0.y += __shfl_down(a0.y, 8, 64);
    a0.z += __shfl_down(a0.z, 8, 64); a0.w += __shfl_down(a0.w, 8, 64);
    a1.x += __shfl_down(a1.x, 8, 64); a1.y += __shfl_down(a1.y, 8, 64);
    a1.z += __shfl_down(a1.z, 8, 64); a1.w += __shfl_down(a1.w, 8, 64);
}

// ---------- fused gather1 + gemm2: yl2 = dis * (relu(dis*(...) + b1) @ W2) ----------
// 16 nodes per block (4 per wave, 16 lanes each).
__global__ __launch_bounds__(256) void gather_gemm2_kernel(
        const int2* __restrict__ csr, const int* __restrict__ rowptr,
        const float* __restrict__ dis, const ushort_t* __restrict__ xl,
        const float* __restrict__ W2, const float* __restrict__ b1,
        ushort_t* __restrict__ xl2) {
    __shared__ float sW[HID * HID];     // 16 KB
    __shared__ float sh[16][HID + 4];   // pad 68: breaks row-alias on ds_write_b128
    int tid = threadIdx.x;
    const float4* W4  = (const float4*)W2;
    float4*       sW4 = (float4*)sW;
    #pragma unroll
    for (int i = 0; i < 4; ++i) sW4[tid + 256 * i] = W4[tid + 256 * i];

    int n0   = blockIdx.x * 16;
    int wv   = tid >> 6;
    int lane = tid & 63;
    int lr   = wv * 4 + (lane >> 4);     // local row 0..15
    int n    = n0 + lr;
    int g    = (lane >> 3) & 1;
    int c0   = (lane & 7) << 3;
    int base = rowptr[n], end = rowptr[n + 1];
    float d  = dis[n];
    float4 a0, a1;
    gather_row16(csr, xl, base, end, n, g, c0, lane, a0, a1);
    if (g == 0) {
        // h = relu(dis[col]*agg + b1), stored directly (no second pass)
        float4 bb0 = *(const float4*)(b1 + c0);
        float4 bb1 = *(const float4*)(b1 + c0 + 4);
        float4 h0 = make_float4(fmaxf(a0.x * d + bb0.x, 0.f), fmaxf(a0.y * d + bb0.y, 0.f),
                                fmaxf(a0.z * d + bb0.z, 0.f), fmaxf(a0.w * d + bb0.w, 0.f));
        float4 h1 = make_float4(fmaxf(a1.x * d + bb1.x, 0.f), fmaxf(a1.y * d + bb1.y, 0.f),
                                fmaxf(a1.z * d + bb1.z, 0.f), fmaxf(a1.w * d + bb1.w, 0.f));
        *(float4*)(&sh[lr][c0])     = h0;
        *(float4*)(&sh[lr][c0 + 4]) = h1;
    }
    __syncthreads();
    // gemm2: each thread computes 4 rows x 1 col; sW value reused 4x per read
    int cc = tid & 63, rq = tid >> 6;
    float acc0 = 0.f, acc1 = 0.f, acc2 = 0.f, acc3 = 0.f;
    #pragma unroll 8
    for (int k = 0; k < HID; ++k) {
        float wk = sW[k * HID + cc];
        acc0 += sh[rq * 4 + 0][k] * wk;
        acc1 += sh[rq * 4 + 1][k] * wk;
        acc2 += sh[rq * 4 + 2][k] * wk;
        acc3 += sh[rq * 4 + 3][k] * wk;
    }
    xl2[(size_t)(n0 + rq * 4 + 0) * HID + cc] = f2bf(acc0 * dis[n0 + rq * 4 + 0]);
    xl2[(size_t)(n0 + rq * 4 + 1) * HID + cc] = f2bf(acc1 * dis[n0 + rq * 4 + 1]);
    xl2[(size_t)(n0 + rq * 4 + 2) * HID + cc] = f2bf(acc2 * dis[n0 + rq * 4 + 2]);
    xl2[(size_t)(n0 + rq * 4 + 3) * HID + cc] = f2bf(acc3 * dis[n0 + rq * 4 + 3]);
}

// ---------- fused gather2 + pool partial: sval[n] = relu(dis*(...)+b2) . Wc ----------
__global__ __launch_bounds__(256) void gather_pool_kernel(
        const int2* __restrict__ csr, const int* __restrict__ rowptr,
        const float* __restrict__ dis, const ushort_t* __restrict__ xl,
        const float* __restrict__ b2, const float* __restrict__ Wc,
        float* __restrict__ sval) {
    int tid  = threadIdx.x;
    int n    = (blockIdx.x * 256 + tid) >> 4;           // grid 6250 exact
    int lane = tid & 63;
    int g    = (lane >> 3) & 1;
    int c0   = (lane & 7) << 3;
    int base = rowptr[n], end = rowptr[n + 1];
    float d  = dis[n];
    float4 a0, a1;
    gather_row16(csr, xl, base, end, n, g, c0, lane, a0, a1);
    // all lanes compute (g==1 lanes produce garbage that is never read)
    float4 bb0 = *(const float4*)(b2 + c0);
    float4 bb1 = *(const float4*)(b2 + c0 + 4);
    float4 wc0 = *(const float4*)(Wc + c0);
    float4 wc1 = *(const float4*)(Wc + c0 + 4);
    float s = fmaxf(a0.x * d + bb0.x, 0.f) * wc0.x + fmaxf(a0.y * d + bb0.y, 0.f) * wc0.y
            + fmaxf(a0.z * d + bb0.z, 0.f) * wc0.z + fmaxf(a0.w * d + bb0.w, 0.f) * wc0.w
            + fmaxf(a1.x * d + bb1.x, 0.f) * wc1.x + fmaxf(a1.y * d + bb1.y, 0.f) * wc1.y
            + fmaxf(a1.z * d + bb1.z, 0.f) * wc1.z + fmaxf(a1.w * d + bb1.w, 0.f) * wc1.w;
    s += __shfl_down(s, 4, 64);
    s += __shfl_down(s, 2, 64);
    s += __shfl_down(s, 1, 64);
    if ((lane & 15) == 0) sval[n] = s;
}

// ---------- final: out[g] = mean(sval over graph range) + bc ----------
__global__ __launch_bounds__(256) void final_out_kernel(const float* __restrict__ sval,
                                                        const int* __restrict__ batch,
                                                        const float* __restrict__ bc,
                                                        float* __restrict__ out) {
    __shared__ float s[256];
    int g = blockIdx.x;   // grid N_GRAPHS
    int lo = 0, hi = N_NODES;
    while (lo < hi) { int m = (lo + hi) >> 1; if (batch[m] < g) lo = m + 1; else hi = m; }
    int start = lo;
    hi = N_NODES;
    while (lo < hi) { int m = (lo + hi) >> 1; if (batch[m] < g + 1) lo = m + 1; else hi = m; }
    int end = lo;
    float acc = 0.f;
    for (int i = start + threadIdx.x; i < end; i += 256) acc += sval[i];
    s[threadIdx.x] = acc;
    __syncthreads();
    #pragma unroll
    for (int off = 128; off > 0; off >>= 1) {
        if (threadIdx.x < off) s[threadIdx.x] += s[threadIdx.x + off];
        __syncthreads();
    }
    if (threadIdx.x == 0)
        out[g] = s[0] / fmaxf((float)(end - start), 1.0f) + bc[0];
}

extern "C" void kernel_launch(void* const* d_in, const int* in_sizes, int n_in,
                              void* d_out, int out_size, void* d_ws, size_t ws_size,
                              hipStream_t stream) {
    const float* x     = (const float*)d_in[0];
    const int*   ei    = (const int*)  d_in[1];
    const float* ew    = (const float*)d_in[2];
    const int*   batch = (const int*)  d_in[3];
    const float* W1    = (const float*)d_in[4];
    const float* b1    = (const float*)d_in[5];
    const float* W2    = (const float*)d_in[6];
    const float* b2    = (const float*)d_in[7];
    const float* Wc    = (const float*)d_in[8];
    const float* bc    = (const float*)d_in[9];
    float* out = (float*)d_out;

    const int* row = ei;
    const int* col = ei + N_EDGES;

    // workspace (~78 MB): recs | xlA | xlB | csr | rowptr | dis | bsum | boff | sval
    // H aliases csr (dead before degcsr writes csr).
    int2*     recs   = (int2*)d_ws;                              // E int2 = 25.6 MB
    ushort_t* xlA    = (ushort_t*)(recs + N_EDGES);              // N*HID bf16
    ushort_t* xlB    = xlA + (size_t)N_NODES * HID;              // N*HID bf16
    int2*     csr    = (int2*)(xlB + (size_t)N_NODES * HID);     // E int2
    int*      rowptr = (int*)(csr + N_EDGES);                    // N_PAD
    float*    dis    = (float*)(rowptr + N_PAD);                 // N_PAD
    int*      bsum   = (int*)(dis + N_PAD);                      // 512
    int*      boff   = bsum + 512;                               // 512
    float*    sval   = (float*)(boff + 512);                     // N_PAD
    int*      H      = (int*)csr;                                // NB*NBLK ints = 401 KB

    bhist_gemm1_kernel<<<NBLK + G1BLK, 256, 0, stream>>>(col, H, x, W1, xlA);
    scan1_kernel    <<<NB,   256, 0, stream>>>(H, bsum);
    bscatter_kernel <<<NBLK, 256, 0, stream>>>(row, col, ew, H, bsum, boff, recs);
    degcsr_kernel   <<<NB,   256, 0, stream>>>(recs, boff, dis, rowptr, csr, xlA);
    gather_gemm2_kernel<<<N_NODES / 16, 256, 0, stream>>>(csr, rowptr, dis, xlA, W2, b1, xlB);
    gather_pool_kernel <<<N_NODES / 16, 256, 0, stream>>>(csr, rowptr, dis, xlB, b2, Wc, sval);
    final_out_kernel<<<N_GRAPHS, 256, 0, stream>>>(sval, batch, bc, out);
}